// Round 6
// baseline (304.478 us; speedup 1.0000x reference)
//
#include <hip/hip_runtime.h>

typedef unsigned short ushort_t;
typedef __attribute__((ext_vector_type(8))) __bf16 bf16x8;
typedef __attribute__((ext_vector_type(4))) float f32x4;

// B=32, N=128, INDIM=32, OUTDIM=64
// X: [32][128][128][32] f32; W: [32][64]; bias: [64]; n_nodes: [32] int
// X1t: [32][64][128][128] bf16  plane rows i, k=j contiguous
// X2t: [32][64][128][128] bf16  plane rows j, k=i contiguous
// out: [32][128][128][64] f32
//
// Masking contract:
//  - lin writes ONLY rows r < n and col-parts part*32 < n (= cols [0,kmax),
//    kmax=ceil32(n)); within them, cols t in [n,kmax) are EXACT zeros.
//    Rows [n,128) are unwritten workspace poison.
//  - mmo reads rows i0+lid / j0+lid unguarded: a poison A-row j contaminates
//    only D row j, a poison B-row i only D col i (MFMA rows/cols isolated);
//    both masked to 0 by select before packing. k-loop < kmax (tail exact 0).
//  - out = f32(bf16(C)) — same rounding as the previous Ct-based pipeline.

__device__ __forceinline__ ushort_t f32_to_bf16(float v) {
    unsigned ui = __float_as_uint(v);
    ui += 0x7fffu + ((ui >> 16) & 1u);   // RNE (finite only)
    return (ushort_t)(ui >> 16);
}

union FragU { bf16x8 f; ushort_t u[8]; };
union Pack4 { ushort_t us[4]; uint2 v; };

// K1 (R1-proven version): Linear(32->64)+bias+ReLU+mask via mfma_16x16x32.
// Grid 2048: blocks 0..1023 pass A (r=i, t=j contiguous), 1024..2047 pass B
// (r=j, t=i strided). Each block handles 4 consecutive r. r>=n rows skipped;
// t-tiles>=n skip loads+MFMA; copy-out truncated to col-parts < ceil32(n).
__global__ __launch_bounds__(256) void lin_mfma_kernel(
        const float* __restrict__ X,
        const float* __restrict__ W1, const float* __restrict__ b1v,
        const float* __restrict__ W2, const float* __restrict__ b2v,
        const int* __restrict__ n_nodes,
        ushort_t* __restrict__ X1t, ushort_t* __restrict__ X2t) {
    __shared__ ushort_t sO[64 * 136];
    const int blk = blockIdx.x;
    const int pass = blk >> 10;
    const int idx = blk & 1023;
    const int b = idx >> 5, rg = idx & 31;           // r-group of 4
    const int n = n_nodes[b];
    if (rg * 4 >= n) return;                         // block-uniform: nothing to write

    const float* W    = pass ? W2  : W1;
    const float* bias = pass ? b2v : b1v;
    ushort_t* Out     = pass ? X2t : X1t;
    const int rstride = pass ? 32 : 4096;
    const int tstride = pass ? 4096 : 32;

    const int u = threadIdx.x;
    const int w = u >> 6, l = u & 63;
    const int quad = l >> 4, lid = l & 15;

    // B-fragments: B[n=e][k=d], lane holds e=ni*16+lid, d=quad*8+j (L1-hot W).
    FragU bfrag[4];
    float bia[4];
    #pragma unroll
    for (int ni = 0; ni < 4; ++ni) {
        const int e = ni * 16 + lid;
        #pragma unroll
        for (int j = 0; j < 8; ++j)
            bfrag[ni].u[j] = f32_to_bf16(W[(quad * 8 + j) * 64 + e]);
        bia[ni] = bias[e];
    }

    for (int q = 0; q < 4; ++q) {
        const int r = rg * 4 + q;
        if (r >= n) break;                           // uniform (r ascending)
        {
            const float* Xb = X + (size_t)b * 524288 + (size_t)r * rstride;
            #pragma unroll
            for (int s = 0; s < 2; ++s) {
                const int mt = w * 2 + s;           // wave w owns m-tiles 2w,2w+1
                const int t0b = mt * 16 + quad * 4;
                if (mt * 16 < n) {
                    const int m = mt * 16 + lid;
                    const float* xr = Xb + (size_t)m * tstride + quad * 8;
                    float4 x0 = *(const float4*)xr;
                    float4 x1 = *(const float4*)(xr + 4);
                    FragU af;
                    af.u[0] = f32_to_bf16(x0.x); af.u[1] = f32_to_bf16(x0.y);
                    af.u[2] = f32_to_bf16(x0.z); af.u[3] = f32_to_bf16(x0.w);
                    af.u[4] = f32_to_bf16(x1.x); af.u[5] = f32_to_bf16(x1.y);
                    af.u[6] = f32_to_bf16(x1.z); af.u[7] = f32_to_bf16(x1.w);
                    #pragma unroll
                    for (int ni = 0; ni < 4; ++ni) {
                        f32x4 acc = {};
                        acc = __builtin_amdgcn_mfma_f32_16x16x32_bf16(
                            af.f, bfrag[ni].f, acc, 0, 0, 0);
                        const int e = ni * 16 + lid;
                        Pack4 pk;
                        #pragma unroll
                        for (int rgi = 0; rgi < 4; ++rgi) {
                            const int t = t0b + rgi;
                            float v = (t < n) ? fmaxf(acc[rgi] + bia[ni], 0.f) : 0.f;
                            pk.us[rgi] = f32_to_bf16(v);
                        }
                        *(uint2*)(sO + e * 136 + t0b) = pk.v;
                    }
                } else {
                    Pack4 pk; pk.us[0] = pk.us[1] = pk.us[2] = pk.us[3] = 0;
                    #pragma unroll
                    for (int ni = 0; ni < 4; ++ni)
                        *(uint2*)(sO + (ni * 16 + lid) * 136 + t0b) = pk.v;
                }
            }
        }
        __syncthreads();
        {   // copy-out: 64 e-rows, only col-parts < ceil32(n) (what mmo reads)
            const int e = u >> 2, part = u & 3;
            if (part * 32 < n) {
                ushort_t* gO = Out + ((size_t)(b * 64 + e) * 128 + r) * 128 + part * 32;
                const ushort_t* sRow = sO + e * 136 + part * 32;
                #pragma unroll
                for (int c = 0; c < 4; ++c)
                    *(uint4*)(gO + c * 8) = *(const uint4*)(sRow + c * 8);
            }
        }
        __syncthreads();
    }
}

// K2' (mmo, fused mm + transpose-out): block = b*64 + it*8 + jt, grid 2048.
// Active block: computes C[i0:i0+16][j0:j0+16] for all 64 e (wave w owns
// e in [w*16, w*16+16), ILP-4 groups), packs to bf16 (== old Ct rounding),
// stages in sC[e][i*18+j] (36.25 KiB, ~2-way banks both sides), then writes
// out[b][i][j][0:64] as coalesced float4 (1 KiB/wave/instr). Inactive tile
// (i0>=n || j0>=n): 64-KiB zero region, no reads.
#define JP 18    // j-pitch (ushorts)
#define EP 290   // e-plane pitch = 16*18+2 (ushorts); word-stride 145 (odd->banks spread)
__global__ __launch_bounds__(256) void mmo_kernel(
        const ushort_t* __restrict__ X1t, const ushort_t* __restrict__ X2t,
        float* __restrict__ out, const int* __restrict__ n_nodes) {
    __shared__ ushort_t sC[64 * EP];
    const int blk = blockIdx.x;
    const int b = blk >> 6, it = (blk >> 3) & 7, jt = blk & 7;
    const int i0 = it * 16, j0 = jt * 16;
    const int n = n_nodes[b];
    const int u = threadIdx.x;
    float* base = out + ((size_t)((b * 128 + i0) * 128 + j0)) * 64;

    if (i0 >= n || j0 >= n) {                        // zero region: 16 x 4 KiB
        float4 z = {0.f, 0.f, 0.f, 0.f};
        #pragma unroll
        for (int il = 0; il < 16; ++il)
            *((float4*)(base + (size_t)il * 8192) + u) = z;
        return;
    }

    const int w = u >> 6, l = u & 63;
    const int quad = l >> 4, lid = l & 15;
    const int kmax = (n + 31) & ~31;
    const size_t pb = (size_t)(b * 64) * 16384;
    const bool iin = (i0 + lid) < n;                 // D col = i = lid

    for (int g = 0; g < 4; ++g) {
        const int e0 = w * 16 + g * 4;               // wave's e-quad
        const ushort_t* Ap[4];                       // X2t rows j (A operand)
        const ushort_t* Bp[4];                       // X1t rows i (B operand)
        #pragma unroll
        for (int ee = 0; ee < 4; ++ee) {
            const size_t ep = pb + (size_t)(e0 + ee) * 16384;
            Ap[ee] = X2t + ep + (size_t)(j0 + lid) * 128 + quad * 8;
            Bp[ee] = X1t + ep + (size_t)(i0 + lid) * 128 + quad * 8;
        }
        f32x4 acc[4] = {};
        for (int k0 = 0; k0 < kmax; k0 += 32) {
            bf16x8 af[4], bf[4];
            #pragma unroll
            for (int ee = 0; ee < 4; ++ee) {
                af[ee] = *(const bf16x8*)(Ap[ee] + k0);
                bf[ee] = *(const bf16x8*)(Bp[ee] + k0);
            }
            #pragma unroll
            for (int ee = 0; ee < 4; ++ee)
                acc[ee] = __builtin_amdgcn_mfma_f32_16x16x32_bf16(
                    af[ee], bf[ee], acc[ee], 0, 0, 0);
        }
        // pack (mask i>=n, j>=n -> 0) into sC; two dword stores (4-B aligned)
        #pragma unroll
        for (int ee = 0; ee < 4; ++ee) {
            Pack4 pk;
            #pragma unroll
            for (int rg = 0; rg < 4; ++rg) {
                const int j = quad * 4 + rg;         // D row = j (reg-contig)
                float v = (iin && (j0 + j) < n) ? acc[ee][rg] : 0.f;
                pk.us[rg] = f32_to_bf16(v);
            }
            ushort_t* s = sC + (e0 + ee) * EP + lid * JP + quad * 4;
            *(unsigned*)(s)     = pk.v.x;
            *(unsigned*)(s + 2) = pk.v.y;
        }
    }
    __syncthreads();

    // epilogue: thread (e4 = u&15, jl = u>>4); 16 il reps; wave writes
    // jl 0..3 x e 0..63 = 1 KiB contiguous per instr.
    const int e4 = u & 15, jl = u >> 4;
    const ushort_t* s0 = sC + (e4 * 4) * EP + jl;
    #pragma unroll
    for (int il = 0; il < 16; ++il) {
        const ushort_t* s = s0 + il * JP;
        float4 vv;
        vv.x = __uint_as_float((unsigned)s[0]      << 16);
        vv.y = __uint_as_float((unsigned)s[EP]     << 16);
        vv.z = __uint_as_float((unsigned)s[2 * EP] << 16);
        vv.w = __uint_as_float((unsigned)s[3 * EP] << 16);
        *(float4*)(base + (size_t)il * 8192 + jl * 64 + e4 * 4) = vv;
    }
}

extern "C" void kernel_launch(void* const* d_in, const int* in_sizes, int n_in,
                              void* d_out, int out_size, void* d_ws, size_t ws_size,
                              hipStream_t stream) {
    const float* X  = (const float*)d_in[0];
    const float* W1 = (const float*)d_in[1];
    const float* b1 = (const float*)d_in[2];
    const float* W2 = (const float*)d_in[3];
    const float* b2 = (const float*)d_in[4];
    const int* nn   = (const int*)d_in[5];
    float* out = (float*)d_out;

    ushort_t* X1t = (ushort_t*)d_ws;          // 64 MiB
    ushort_t* X2t = X1t + 33554432;           // +64 MiB

    lin_mfma_kernel<<<2048, 256, 0, stream>>>(X, W1, b1, W2, b2, nn, X1t, X2t);
    mmo_kernel<<<2048, 256, 0, stream>>>(X1t, X2t, out, nn);
}

// Round 8
// 262.468 us; speedup vs baseline: 1.1601x; 1.1601x over previous
//
#include <hip/hip_runtime.h>

typedef unsigned short ushort_t;
typedef __attribute__((ext_vector_type(8))) __bf16 bf16x8;
typedef __attribute__((ext_vector_type(4))) float f32x4;

// B=32, N=128, INDIM=32, OUTDIM=64
// X: [32][128][128][32] f32; W: [32][64]; bias: [64]; n_nodes: [32] int
// X1t: [32][64][128][128] bf16  plane rows i, k=j contiguous
// X2t: [32][64][128][128] bf16  plane rows j, k=i contiguous
// Ct : aliases X1t (per-(b,e)-plane exclusive in K2)
// out: [32][128][128][64] f32
//
// Masking contract:
//  - lin writes ONLY rows r < n and col-parts part*32 < n (= cols [0,kmax));
//    within them, cols t in [n,kmax) are EXACT zeros. Rows [n,128) poison.
//  - mm stages rows < ceil16(n) (poison rows contaminate only C row j>=n /
//    col i>=n), k-loop < kmax; stores only i<n rows, j-chunks c*8<n.
//  - tr masks j>=n inside the boundary chunk on load.

__device__ __forceinline__ ushort_t f32_to_bf16(float v) {
    unsigned ui = __float_as_uint(v);
    ui += 0x7fffu + ((ui >> 16) & 1u);   // RNE (finite only)
    return (ushort_t)(ui >> 16);
}

union FragU { bf16x8 f; ushort_t u[8]; };
union Pack4 { ushort_t us[4]; uint2 v; };

// K1 (R1-proven): Linear(32->64)+bias+ReLU+mask via mfma_16x16x32.
// Grid 2048: blocks 0..1023 pass A (r=i, t=j contiguous), 1024..2047 pass B
// (r=j, t=i strided). 4 consecutive r per block; r>=n skipped; t-tiles>=n
// skip loads+MFMA; copy-out truncated to col-parts < ceil32(n).
__global__ __launch_bounds__(256) void lin_mfma_kernel(
        const float* __restrict__ X,
        const float* __restrict__ W1, const float* __restrict__ b1v,
        const float* __restrict__ W2, const float* __restrict__ b2v,
        const int* __restrict__ n_nodes,
        ushort_t* __restrict__ X1t, ushort_t* __restrict__ X2t) {
    __shared__ ushort_t sO[64 * 136];
    const int blk = blockIdx.x;
    const int pass = blk >> 10;
    const int idx = blk & 1023;
    const int b = idx >> 5, rg = idx & 31;           // r-group of 4
    const int n = n_nodes[b];
    if (rg * 4 >= n) return;                         // block-uniform: nothing to write

    const float* W    = pass ? W2  : W1;
    const float* bias = pass ? b2v : b1v;
    ushort_t* Out     = pass ? X2t : X1t;
    const int rstride = pass ? 32 : 4096;
    const int tstride = pass ? 4096 : 32;

    const int u = threadIdx.x;
    const int w = u >> 6, l = u & 63;
    const int quad = l >> 4, lid = l & 15;

    // B-fragments: B[n=e][k=d], lane holds e=ni*16+lid, d=quad*8+j (L1-hot W).
    FragU bfrag[4];
    float bia[4];
    #pragma unroll
    for (int ni = 0; ni < 4; ++ni) {
        const int e = ni * 16 + lid;
        #pragma unroll
        for (int j = 0; j < 8; ++j)
            bfrag[ni].u[j] = f32_to_bf16(W[(quad * 8 + j) * 64 + e]);
        bia[ni] = bias[e];
    }

    for (int q = 0; q < 4; ++q) {
        const int r = rg * 4 + q;
        if (r >= n) break;                           // uniform (r ascending)
        {
            const float* Xb = X + (size_t)b * 524288 + (size_t)r * rstride;
            #pragma unroll
            for (int s = 0; s < 2; ++s) {
                const int mt = w * 2 + s;           // wave w owns m-tiles 2w,2w+1
                const int t0b = mt * 16 + quad * 4;
                if (mt * 16 < n) {
                    const int m = mt * 16 + lid;
                    const float* xr = Xb + (size_t)m * tstride + quad * 8;
                    float4 x0 = *(const float4*)xr;
                    float4 x1 = *(const float4*)(xr + 4);
                    FragU af;
                    af.u[0] = f32_to_bf16(x0.x); af.u[1] = f32_to_bf16(x0.y);
                    af.u[2] = f32_to_bf16(x0.z); af.u[3] = f32_to_bf16(x0.w);
                    af.u[4] = f32_to_bf16(x1.x); af.u[5] = f32_to_bf16(x1.y);
                    af.u[6] = f32_to_bf16(x1.z); af.u[7] = f32_to_bf16(x1.w);
                    #pragma unroll
                    for (int ni = 0; ni < 4; ++ni) {
                        f32x4 acc = {};
                        acc = __builtin_amdgcn_mfma_f32_16x16x32_bf16(
                            af.f, bfrag[ni].f, acc, 0, 0, 0);
                        const int e = ni * 16 + lid;
                        Pack4 pk;
                        #pragma unroll
                        for (int rgi = 0; rgi < 4; ++rgi) {
                            const int t = t0b + rgi;
                            float v = (t < n) ? fmaxf(acc[rgi] + bia[ni], 0.f) : 0.f;
                            pk.us[rgi] = f32_to_bf16(v);
                        }
                        *(uint2*)(sO + e * 136 + t0b) = pk.v;
                    }
                } else {
                    Pack4 pk; pk.us[0] = pk.us[1] = pk.us[2] = pk.us[3] = 0;
                    #pragma unroll
                    for (int ni = 0; ni < 4; ++ni)
                        *(uint2*)(sO + (ni * 16 + lid) * 136 + t0b) = pk.v;
                }
            }
        }
        __syncthreads();
        {   // copy-out: 64 e-rows, only col-parts < ceil32(n) (what mm reads)
            const int e = u >> 2, part = u & 3;
            if (part * 32 < n) {
                ushort_t* gO = Out + ((size_t)(b * 64 + e) * 128 + r) * 128 + part * 32;
                const ushort_t* sRow = sO + e * 136 + part * 32;
                #pragma unroll
                for (int c = 0; c < 4; ++c)
                    *(uint4*)(gO + c * 8) = *(const uint4*)(sRow + c * 8);
            }
        }
        __syncthreads();
    }
}

// K2 (mm v2, swizzle FIXED): per-(b,e) 128x128x128 bf16 MFMA, LDS-staged.
// Staging: fully-coalesced 16-B/lane row bursts; 16-B chunk index XORed with
// (row&7) on BOTH write and read (same 3-bit involution; R7's bug was
// write-side using row&15). A|B = exactly 64 KiB; sC (pitch 136) reuses the
// same buffer after a barrier. k-loop < kmax; inactive tiles skip
// reads+MFMA. Stores only i<n rows, j-chunks c*8<n.
__global__ __launch_bounds__(256) void mm_kernel(
        const ushort_t* __restrict__ X1t, const ushort_t* __restrict__ X2t,
        ushort_t* __restrict__ Ct, const int* __restrict__ n_nodes) {
    __shared__ uint4 sMem4[4096];                    // 64 KiB total
    const int blk = blockIdx.x;
    const size_t plane = (size_t)blk * 16384;        // blk = b*64+e
    const int n = n_nodes[blk >> 6];
    const int kmax = (n + 31) & ~31;
    const int rmax16 = (n + 15) >> 4;                // #16-row groups staged
    const int cmax = kmax >> 3;                      // #16-B chunks per row
    const ushort_t* Aj = X2t + plane;                // rows j, k=i contiguous
    const ushort_t* Bi = X1t + plane;                // rows i, k=j contiguous
    uint4* sA4 = sMem4;                              // [row][16 units]
    uint4* sB4 = sMem4 + 2048;
    const int u = threadIdx.x;
    const int w = u >> 6, l = u & 63;
    const int quad = l >> 4, lid = l & 15;

    {   // stage: thread (rq=u>>4, c=u&15); global 16 B/lane, 4 rows/wave/instr
        const int rq = u >> 4, c = u & 15;
        if (c < cmax) {
            const int cs = c ^ (rq & 7);             // r&7 == rq&7 (r=rb*16+rq)
            for (int rb = 0; rb < rmax16; ++rb) {
                const int r = rb * 16 + rq;
                sA4[r * 16 + cs] = *(const uint4*)(Aj + (size_t)r * 128 + c * 8);
                sB4[r * 16 + cs] = *(const uint4*)(Bi + (size_t)r * 128 + c * 8);
            }
        }
    }
    __syncthreads();

    const int wj = (w >> 1) * 64, wi = (w & 1) * 64;
    bool aAct[4], bAct[4];
    #pragma unroll
    for (int mj = 0; mj < 4; ++mj) aAct[mj] = (wj + mj * 16) < n;
    #pragma unroll
    for (int ni = 0; ni < 4; ++ni) bAct[ni] = (wi + ni * 16) < n;
    f32x4 acc[4][4] = {};                            // [mj][ni]

    const bf16x8* sAf = (const bf16x8*)sA4;
    const bf16x8* sBf = (const bf16x8*)sB4;
    const int lsw = lid & 7;                         // frag row&7 == lid&7
    for (int k0 = 0; k0 < kmax; k0 += 32) {
        const int kb = k0 >> 3;
        bf16x8 af[4], bfr[4];
        #pragma unroll
        for (int mj = 0; mj < 4; ++mj)
            if (aAct[mj])
                af[mj] = sAf[(wj + mj * 16 + lid) * 16 + ((kb + quad) ^ lsw)];
        #pragma unroll
        for (int ni = 0; ni < 4; ++ni)
            if (bAct[ni])
                bfr[ni] = sBf[(wi + ni * 16 + lid) * 16 + ((kb + quad) ^ lsw)];
        #pragma unroll
        for (int mj = 0; mj < 4; ++mj)
            #pragma unroll
            for (int ni = 0; ni < 4; ++ni)
                if (aAct[mj] && bAct[ni])
                    acc[mj][ni] = __builtin_amdgcn_mfma_f32_16x16x32_bf16(
                        af[mj], bfr[ni], acc[mj][ni], 0, 0, 0);
    }
    __syncthreads();                                 // all frag reads done

    ushort_t* sC = (ushort_t*)sMem4;                 // pitch 136, reuses A|B
    #pragma unroll
    for (int mj = 0; mj < 4; ++mj)
        #pragma unroll
        for (int ni = 0; ni < 4; ++ni) {
            const int j0 = wj + mj * 16 + quad * 4;  // C row = j (reg-contiguous)
            const int i  = wi + ni * 16 + lid;       // C col = i
            Pack4 pk;
            #pragma unroll
            for (int rg = 0; rg < 4; ++rg)
                pk.us[rg] = f32_to_bf16(acc[mj][ni][rg]);
            *(uint2*)(sC + i * 136 + j0) = pk.v;
        }
    __syncthreads();
    ushort_t* Cp = Ct + plane;
    #pragma unroll
    for (int it = 0; it < 8; ++it) {
        int idx = it * 256 + u;
        int i = idx >> 4, c = idx & 15;
        if (i < n && c * 8 < n)
            *(uint4*)(Cp + (size_t)idx * 8) = *(const uint4*)(sC + i * 136 + c * 8);
    }
}

// K3: block = (b, i). i>=n: write 32 KB zeros, no reads. Else gather
// Ct[b][e][i][j<n] (coalesced) into LDS sT[e][j] f32 stride 129, masking
// j>=n inside the boundary chunk and zero-filling j-tail chunks, then write
// out[b][i][:][:] as one contiguous 32-KB region.
__global__ __launch_bounds__(256) void tr_kernel(
        const ushort_t* __restrict__ Ct, float* __restrict__ out,
        const int* __restrict__ n_nodes) {
    __shared__ float sT[64 * 129];
    const int blk = blockIdx.x;                      // b*128 + i
    const int b = blk >> 7, i = blk & 127;
    const int u = threadIdx.x;
    const int n = n_nodes[b];
    float* ob = out + ((size_t)b * 16384 + (size_t)i * 128) * 64;

    if (i >= n) {                                    // block-uniform early-out
        float4 z = {0.f, 0.f, 0.f, 0.f};
        #pragma unroll
        for (int it = 0; it < 8; ++it)
            *(float4*)(ob + (size_t)(it * 256 + u) * 4) = z;
        return;
    }

    const ushort_t* Cb = Ct + (size_t)b * 1048576 + (size_t)i * 128;
    #pragma unroll
    for (int it = 0; it < 4; ++it) {
        int idx = it * 256 + u;
        int e = idx >> 4, c = idx & 15;
        float* dst = sT + e * 129 + c * 8;
        const int rem = n - c * 8;                   // #valid j in this chunk
        if (rem >= 8) {
            uint4 v = *(const uint4*)(Cb + (size_t)e * 16384 + c * 8);
            dst[0] = __uint_as_float(v.x << 16);
            dst[1] = __uint_as_float(v.x & 0xffff0000u);
            dst[2] = __uint_as_float(v.y << 16);
            dst[3] = __uint_as_float(v.y & 0xffff0000u);
            dst[4] = __uint_as_float(v.z << 16);
            dst[5] = __uint_as_float(v.z & 0xffff0000u);
            dst[6] = __uint_as_float(v.w << 16);
            dst[7] = __uint_as_float(v.w & 0xffff0000u);
        } else if (rem > 0) {                        // boundary chunk: mask j>=n
            uint4 v = *(const uint4*)(Cb + (size_t)e * 16384 + c * 8);
            float tmp[8];
            tmp[0] = __uint_as_float(v.x << 16);
            tmp[1] = __uint_as_float(v.x & 0xffff0000u);
            tmp[2] = __uint_as_float(v.y << 16);
            tmp[3] = __uint_as_float(v.y & 0xffff0000u);
            tmp[4] = __uint_as_float(v.z << 16);
            tmp[5] = __uint_as_float(v.z & 0xffff0000u);
            tmp[6] = __uint_as_float(v.w << 16);
            tmp[7] = __uint_as_float(v.w & 0xffff0000u);
            #pragma unroll
            for (int t = 0; t < 8; ++t) dst[t] = (t < rem) ? tmp[t] : 0.f;
        } else {
            #pragma unroll
            for (int t = 0; t < 8; ++t) dst[t] = 0.f;
        }
    }
    __syncthreads();

    #pragma unroll
    for (int it = 0; it < 8; ++it) {
        int idx = it * 256 + u;                      // float4 over flat (j,e)
        int j = idx >> 4, e0 = (idx & 15) * 4;
        float4 vv;
        vv.x = sT[(e0 + 0) * 129 + j];
        vv.y = sT[(e0 + 1) * 129 + j];
        vv.z = sT[(e0 + 2) * 129 + j];
        vv.w = sT[(e0 + 3) * 129 + j];
        *(float4*)(ob + (size_t)idx * 4) = vv;
    }
}

extern "C" void kernel_launch(void* const* d_in, const int* in_sizes, int n_in,
                              void* d_out, int out_size, void* d_ws, size_t ws_size,
                              hipStream_t stream) {
    const float* X  = (const float*)d_in[0];
    const float* W1 = (const float*)d_in[1];
    const float* b1 = (const float*)d_in[2];
    const float* W2 = (const float*)d_in[3];
    const float* b2 = (const float*)d_in[4];
    const int* nn   = (const int*)d_in[5];
    float* out = (float*)d_out;

    ushort_t* X1t = (ushort_t*)d_ws;          // 64 MiB
    ushort_t* X2t = X1t + 33554432;           // +64 MiB
    ushort_t* Ct  = X1t;                      // alias (per-plane exclusive in K2)

    lin_mfma_kernel<<<2048, 256, 0, stream>>>(X, W1, b1, W2, b2, nn, X1t, X2t);
    mm_kernel<<<2048, 256, 0, stream>>>(X1t, X2t, Ct, nn);
    tr_kernel<<<4096, 256, 0, stream>>>(Ct, out, nn);
}

// Round 9
// 260.445 us; speedup vs baseline: 1.1691x; 1.0078x over previous
//
#include <hip/hip_runtime.h>

typedef unsigned short ushort_t;
typedef __attribute__((ext_vector_type(8))) __bf16 bf16x8;
typedef __attribute__((ext_vector_type(4))) float f32x4;

// B=32, N=128, INDIM=32, OUTDIM=64
// X: [32][128][128][32] f32; W: [32][64]; bias: [64]; n_nodes: [32] int
// X1t: [32][64][128][128] bf16  plane rows i, k=j contiguous
// X2t: [32][64][128][128] bf16  plane rows j, k=i contiguous
// Ct : aliases X1t (per-(b,e)-plane exclusive in K2)
// out: [32][128][128][64] f32
//
// Masking contract:
//  - lin writes ONLY rows r < n and col-parts part*32 < n (= cols [0,kmax));
//    within them, cols t in [n,kmax) are EXACT zeros. Rows [n,128) poison.
//  - mm stages rows < ceil16(n) (poison rows contaminate only C row j>=n /
//    col i>=n), k-loop < kmax; stores only i<n rows, j-chunks c*8<n.
//  - tr masks j>=n inside the boundary chunk on load.
//
// bf16 pack: hardware (__bf16) cast = v_cvt_pk_bf16_f32, RNE — bit-identical
// to the previous manual RNE for finite values (all values here finite).

__device__ __forceinline__ __bf16 cvt_bf16(float v) { return (__bf16)v; }

union FragU  { bf16x8 f; __bf16 h[8]; };
union Pack4  { __bf16 h[4]; uint2 v; };

// K1: Linear(32->64)+bias+ReLU+mask via mfma_16x16x32.
// Grid 2048: blocks 0..1023 pass A (r=i, t=j contiguous), 1024..2047 pass B
// (r=j, t=i strided 128-B gathers). 4 consecutive r per block; r>=n skipped;
// t-tiles>=n skip loads+MFMA; copy-out truncated to col-parts < ceil32(n).
__global__ __launch_bounds__(256) void lin_mfma_kernel(
        const float* __restrict__ X,
        const float* __restrict__ W1, const float* __restrict__ b1v,
        const float* __restrict__ W2, const float* __restrict__ b2v,
        const int* __restrict__ n_nodes,
        ushort_t* __restrict__ X1t, ushort_t* __restrict__ X2t) {
    __shared__ ushort_t sO[64 * 136];
    const int blk = blockIdx.x;
    const int pass = blk >> 10;
    const int idx = blk & 1023;
    const int b = idx >> 5, rg = idx & 31;           // r-group of 4
    const int n = n_nodes[b];
    if (rg * 4 >= n) return;                         // block-uniform: nothing to write

    const float* W    = pass ? W2  : W1;
    const float* bias = pass ? b2v : b1v;
    ushort_t* Out     = pass ? X2t : X1t;
    const int rstride = pass ? 32 : 4096;
    const int tstride = pass ? 4096 : 32;

    const int u = threadIdx.x;
    const int w = u >> 6, l = u & 63;
    const int quad = l >> 4, lid = l & 15;

    // B-fragments: B[n=e][k=d], lane holds e=ni*16+lid, d=quad*8+j (L1-hot W).
    FragU bfrag[4];
    float bia[4];
    #pragma unroll
    for (int ni = 0; ni < 4; ++ni) {
        const int e = ni * 16 + lid;
        #pragma unroll
        for (int j = 0; j < 8; ++j)
            bfrag[ni].h[j] = cvt_bf16(W[(quad * 8 + j) * 64 + e]);
        bia[ni] = bias[e];
    }

    for (int q = 0; q < 4; ++q) {
        const int r = rg * 4 + q;
        if (r >= n) break;                           // uniform (r ascending)
        {
            const float* Xb = X + (size_t)b * 524288 + (size_t)r * rstride;
            #pragma unroll
            for (int s = 0; s < 2; ++s) {
                const int mt = w * 2 + s;           // wave w owns m-tiles 2w,2w+1
                const int t0b = mt * 16 + quad * 4;
                if (mt * 16 < n) {
                    const int m = mt * 16 + lid;
                    const float* xr = Xb + (size_t)m * tstride + quad * 8;
                    float4 x0 = *(const float4*)xr;
                    float4 x1 = *(const float4*)(xr + 4);
                    FragU af;
                    af.h[0] = cvt_bf16(x0.x); af.h[1] = cvt_bf16(x0.y);
                    af.h[2] = cvt_bf16(x0.z); af.h[3] = cvt_bf16(x0.w);
                    af.h[4] = cvt_bf16(x1.x); af.h[5] = cvt_bf16(x1.y);
                    af.h[6] = cvt_bf16(x1.z); af.h[7] = cvt_bf16(x1.w);
                    #pragma unroll
                    for (int ni = 0; ni < 4; ++ni) {
                        f32x4 acc = {};
                        acc = __builtin_amdgcn_mfma_f32_16x16x32_bf16(
                            af.f, bfrag[ni].f, acc, 0, 0, 0);
                        const int e = ni * 16 + lid;
                        Pack4 pk;
                        #pragma unroll
                        for (int rgi = 0; rgi < 4; ++rgi) {
                            const int t = t0b + rgi;
                            float v = (t < n) ? fmaxf(acc[rgi] + bia[ni], 0.f) : 0.f;
                            pk.h[rgi] = cvt_bf16(v);
                        }
                        *(uint2*)(sO + e * 136 + t0b) = pk.v;
                    }
                } else {
                    Pack4 pk;
                    pk.h[0] = pk.h[1] = pk.h[2] = pk.h[3] = cvt_bf16(0.f);
                    #pragma unroll
                    for (int ni = 0; ni < 4; ++ni)
                        *(uint2*)(sO + (ni * 16 + lid) * 136 + t0b) = pk.v;
                }
            }
        }
        __syncthreads();
        {   // copy-out: 64 e-rows, only col-parts < ceil32(n) (what mm reads)
            const int e = u >> 2, part = u & 3;
            if (part * 32 < n) {
                ushort_t* gO = Out + ((size_t)(b * 64 + e) * 128 + r) * 128 + part * 32;
                const ushort_t* sRow = sO + e * 136 + part * 32;
                #pragma unroll
                for (int c = 0; c < 4; ++c)
                    *(uint4*)(gO + c * 8) = *(const uint4*)(sRow + c * 8);
            }
        }
        __syncthreads();
    }
}

// K2 (mm v3): per-(b,e) 128x128x128 bf16 MFMA; k-chunked (32 cols),
// double-buffered LDS staging, row pitch 5 uint4 (80 B; 2-way banks = free,
// no XOR). LDS 40 KiB -> 4 blocks/CU (was 2 at 64 KiB). STAGE(t+1) issued
// before compute(t) so global latency hides under MFMA. sC (pitch 136,
// 34.8 KiB) reuses the staging buffer after the final barrier.
#define MMP 5                                        // uint4 per 32-col row
__global__ __launch_bounds__(256) void mm_kernel(
        const ushort_t* __restrict__ X1t, const ushort_t* __restrict__ X2t,
        ushort_t* __restrict__ Ct, const int* __restrict__ n_nodes) {
    __shared__ uint4 sS[2 * 2 * 128 * MMP];          // 40960 B
    const int blk = blockIdx.x;
    const size_t plane = (size_t)blk * 16384;        // blk = b*64+e
    const int n = n_nodes[blk >> 6];
    const int kmax = (n + 31) & ~31;
    const int T = kmax >> 5;                         // 1..4 k-chunks
    const int R = (n + 15) & ~15;                    // rows staged
    const ushort_t* Aj = X2t + plane;                // rows j, k=i contiguous
    const ushort_t* Bi = X1t + plane;                // rows i, k=j contiguous
    const int u = threadIdx.x;
    const int w = u >> 6, l = u & 63;
    const int quad = l >> 4, lid = l & 15;
    const int srow = u >> 2, sc = u & 3;             // staging (row, 16-B unit)

    auto STAGE = [&](int t, int bsel) {
        uint4* dA = sS + bsel * (2 * 128 * MMP);
        uint4* dB = dA + 128 * MMP;
        const ushort_t* gA = Aj + t * 32 + sc * 8;
        const ushort_t* gB = Bi + t * 32 + sc * 8;
        #pragma unroll
        for (int p = 0; p < 2; ++p) {
            const int r = p * 64 + srow;
            if (r < R) {
                dA[r * MMP + sc] = *(const uint4*)(gA + (size_t)r * 128);
                dB[r * MMP + sc] = *(const uint4*)(gB + (size_t)r * 128);
            }
        }
    };

    const int wj = (w >> 1) * 64, wi = (w & 1) * 64;
    bool aAct[4], bAct[4];
    #pragma unroll
    for (int mj = 0; mj < 4; ++mj) aAct[mj] = (wj + mj * 16) < n;
    #pragma unroll
    for (int ni = 0; ni < 4; ++ni) bAct[ni] = (wi + ni * 16) < n;
    f32x4 acc[4][4] = {};                            // [mj][ni]

    STAGE(0, 0);
    __syncthreads();
    for (int t = 0; t < T; ++t) {
        if (t + 1 < T) STAGE(t + 1, (t + 1) & 1);    // prefetch next chunk
        const uint4* bA = sS + (t & 1) * (2 * 128 * MMP);
        const uint4* bB = bA + 128 * MMP;
        bf16x8 af[4], bfr[4];
        #pragma unroll
        for (int mj = 0; mj < 4; ++mj)
            if (aAct[mj])
                af[mj] = *(const bf16x8*)&bA[(wj + mj * 16 + lid) * MMP + quad];
        #pragma unroll
        for (int ni = 0; ni < 4; ++ni)
            if (bAct[ni])
                bfr[ni] = *(const bf16x8*)&bB[(wi + ni * 16 + lid) * MMP + quad];
        #pragma unroll
        for (int mj = 0; mj < 4; ++mj)
            #pragma unroll
            for (int ni = 0; ni < 4; ++ni)
                if (aAct[mj] && bAct[ni])
                    acc[mj][ni] = __builtin_amdgcn_mfma_f32_16x16x32_bf16(
                        af[mj], bfr[ni], acc[mj][ni], 0, 0, 0);
        __syncthreads();                             // stage done + reads done
    }

    ushort_t* sC = (ushort_t*)sS;                    // pitch 136, reuses stage
    #pragma unroll
    for (int mj = 0; mj < 4; ++mj)
        #pragma unroll
        for (int ni = 0; ni < 4; ++ni) {
            const int j0 = wj + mj * 16 + quad * 4;  // C row = j (reg-contiguous)
            const int i  = wi + ni * 16 + lid;       // C col = i
            Pack4 pk;
            #pragma unroll
            for (int rg = 0; rg < 4; ++rg)
                pk.h[rg] = cvt_bf16(acc[mj][ni][rg]);
            *(uint2*)(sC + i * 136 + j0) = pk.v;
        }
    __syncthreads();
    ushort_t* Cp = Ct + plane;
    #pragma unroll
    for (int it = 0; it < 8; ++it) {
        int idx = it * 256 + u;
        int i = idx >> 4, c = idx & 15;
        if (i < n && c * 8 < n)
            *(uint4*)(Cp + (size_t)idx * 8) = *(const uint4*)(sC + i * 136 + c * 8);
    }
}

// K3: block = (b, i). i>=n: write 32 KB zeros, no reads. Else gather
// Ct[b][e][i][j<n] (coalesced) into LDS sT[e][j] f32 stride 129, masking
// j>=n inside the boundary chunk and zero-filling j-tail chunks, then write
// out[b][i][:][:] as one contiguous 32-KB region.
__global__ __launch_bounds__(256) void tr_kernel(
        const ushort_t* __restrict__ Ct, float* __restrict__ out,
        const int* __restrict__ n_nodes) {
    __shared__ float sT[64 * 129];
    const int blk = blockIdx.x;                      // b*128 + i
    const int b = blk >> 7, i = blk & 127;
    const int u = threadIdx.x;
    const int n = n_nodes[b];
    float* ob = out + ((size_t)b * 16384 + (size_t)i * 128) * 64;

    if (i >= n) {                                    // block-uniform early-out
        float4 z = {0.f, 0.f, 0.f, 0.f};
        #pragma unroll
        for (int it = 0; it < 8; ++it)
            *(float4*)(ob + (size_t)(it * 256 + u) * 4) = z;
        return;
    }

    const ushort_t* Cb = Ct + (size_t)b * 1048576 + (size_t)i * 128;
    #pragma unroll
    for (int it = 0; it < 4; ++it) {
        int idx = it * 256 + u;
        int e = idx >> 4, c = idx & 15;
        float* dst = sT + e * 129 + c * 8;
        const int rem = n - c * 8;                   // #valid j in this chunk
        if (rem >= 8) {
            uint4 v = *(const uint4*)(Cb + (size_t)e * 16384 + c * 8);
            dst[0] = __uint_as_float(v.x << 16);
            dst[1] = __uint_as_float(v.x & 0xffff0000u);
            dst[2] = __uint_as_float(v.y << 16);
            dst[3] = __uint_as_float(v.y & 0xffff0000u);
            dst[4] = __uint_as_float(v.z << 16);
            dst[5] = __uint_as_float(v.z & 0xffff0000u);
            dst[6] = __uint_as_float(v.w << 16);
            dst[7] = __uint_as_float(v.w & 0xffff0000u);
        } else if (rem > 0) {                        // boundary chunk: mask j>=n
            uint4 v = *(const uint4*)(Cb + (size_t)e * 16384 + c * 8);
            float tmp[8];
            tmp[0] = __uint_as_float(v.x << 16);
            tmp[1] = __uint_as_float(v.x & 0xffff0000u);
            tmp[2] = __uint_as_float(v.y << 16);
            tmp[3] = __uint_as_float(v.y & 0xffff0000u);
            tmp[4] = __uint_as_float(v.z << 16);
            tmp[5] = __uint_as_float(v.z & 0xffff0000u);
            tmp[6] = __uint_as_float(v.w << 16);
            tmp[7] = __uint_as_float(v.w & 0xffff0000u);
            #pragma unroll
            for (int t = 0; t < 8; ++t) dst[t] = (t < rem) ? tmp[t] : 0.f;
        } else {
            #pragma unroll
            for (int t = 0; t < 8; ++t) dst[t] = 0.f;
        }
    }
    __syncthreads();

    #pragma unroll
    for (int it = 0; it < 8; ++it) {
        int idx = it * 256 + u;                      // float4 over flat (j,e)
        int j = idx >> 4, e0 = (idx & 15) * 4;
        float4 vv;
        vv.x = sT[(e0 + 0) * 129 + j];
        vv.y = sT[(e0 + 1) * 129 + j];
        vv.z = sT[(e0 + 2) * 129 + j];
        vv.w = sT[(e0 + 3) * 129 + j];
        *(float4*)(ob + (size_t)idx * 4) = vv;
    }
}

extern "C" void kernel_launch(void* const* d_in, const int* in_sizes, int n_in,
                              void* d_out, int out_size, void* d_ws, size_t ws_size,
                              hipStream_t stream) {
    const float* X  = (const float*)d_in[0];
    const float* W1 = (const float*)d_in[1];
    const float* b1 = (const float*)d_in[2];
    const float* W2 = (const float*)d_in[3];
    const float* b2 = (const float*)d_in[4];
    const int* nn   = (const int*)d_in[5];
    float* out = (float*)d_out;

    ushort_t* X1t = (ushort_t*)d_ws;          // 64 MiB
    ushort_t* X2t = X1t + 33554432;           // +64 MiB
    ushort_t* Ct  = X1t;                      // alias (per-plane exclusive in K2)

    lin_mfma_kernel<<<2048, 256, 0, stream>>>(X, W1, b1, W2, b2, nn, X1t, X2t);
    mm_kernel<<<2048, 256, 0, stream>>>(X1t, X2t, Ct, nn);
    tr_kernel<<<4096, 256, 0, stream>>>(Ct, out, nn);
}